// Round 2
// baseline (2856.961 us; speedup 1.0000x reference)
//
#include <hip/hip_runtime.h>
#include <math.h>

#define LEAKY(x) ((x) > 0.0f ? (x) : 0.01f*(x))

// ---------------- weight relayout: W2 [32][16][7][7] -> [k][32], W3 [64][32][5][5] -> [k][64]
__global__ __launch_bounds__(256) void prep_weights(
    const float* __restrict__ W2, const float* __restrict__ W3,
    float* __restrict__ w2r, float* __restrict__ w3r)
{
  int i = blockIdx.x*256 + threadIdx.x;
  if (i < 25088) {
    int co = i & 31; int k = i >> 5;
    w2r[k*32 + co] = W2[co*784 + k];
  }
  if (i < 51200) {
    int co = i & 63; int k = i >> 6;
    w3r[k*64 + co] = W3[co*800 + k];
  }
}

// ---------------- conv1 (3->16, 9x9, pad 1) + maxpool 7/5 + leaky ----------------
// block = (pr 0..37, n 0..239), 576 threads. Thread = (cog{0,1}, pc 0..37, ph 0..6),
// computes 8 co x 7 pw conv values at conv-row 5*pr+ph, then max over pw; cross-ph max via LDS.
__global__ __launch_bounds__(576) void conv1_pool(
    const float* __restrict__ X, const float* __restrict__ W1,
    const float* __restrict__ b1, float* __restrict__ out1)
{
  const int pr = blockIdx.x;
  const int n  = blockIdx.y;
  __shared__ float sIn[3][15][202];
  __shared__ __align__(16) float sW[4256];   // weights [27][9][16] during compute; pm [2][38][7][8] after
  const int tid = threadIdx.x;

  for (int idx = tid; idx < 9090; idx += 576) {
    int ci = idx / 3030;
    int rem = idx - ci*3030;
    int lr = rem / 202;
    int lc = rem - lr*202;
    int r = 5*pr - 1 + lr;
    int c = lc - 1;
    float v = 0.0f;
    if (r >= 0 && r < 200 && c >= 0 && c < 200)
      v = X[((n*3 + ci)*200 + r)*200 + c];
    sIn[ci][lr][lc] = v;
  }
  for (int idx = tid; idx < 3888; idx += 576) {
    int co = idx & 15;
    int kw = (idx >> 4) % 9;
    int kh = (idx / 144) % 9;
    int ci = idx / 1296;
    sW[((ci*9 + kh)*9 + kw)*16 + co] = W1[(co*3 + ci)*81 + kh*9 + kw];
  }
  __syncthreads();

  float m8[8];
  const bool active = tid < 532;
  int pc = 0, ph = 0, cog = 0;
  if (active) {
    pc  = tid % 38;
    ph  = (tid / 38) % 7;
    cog = tid / 266;

    float cv[8][7];
    #pragma unroll
    for (int j = 0; j < 8; ++j) {
      float bv = b1[cog*8 + j];
      #pragma unroll
      for (int pw = 0; pw < 7; ++pw) cv[j][pw] = bv;
    }

    for (int ci = 0; ci < 3; ++ci) {
      for (int kh = 0; kh < 9; ++kh) {
        const float* __restrict__ ip = &sIn[ci][ph + kh][5*pc];
        float xv[15];
        #pragma unroll
        for (int t = 0; t < 15; ++t) xv[t] = ip[t];
        const float4* __restrict__ wp = (const float4*)&sW[(ci*9 + kh)*144 + cog*8];
        #pragma unroll
        for (int kw = 0; kw < 9; ++kw) {
          float4 wa = wp[kw*4];
          float4 wb = wp[kw*4 + 1];
          #pragma unroll
          for (int pw = 0; pw < 7; ++pw) {
            float x = xv[pw + kw];
            cv[0][pw] = fmaf(x, wa.x, cv[0][pw]);
            cv[1][pw] = fmaf(x, wa.y, cv[1][pw]);
            cv[2][pw] = fmaf(x, wa.z, cv[2][pw]);
            cv[3][pw] = fmaf(x, wa.w, cv[3][pw]);
            cv[4][pw] = fmaf(x, wb.x, cv[4][pw]);
            cv[5][pw] = fmaf(x, wb.y, cv[5][pw]);
            cv[6][pw] = fmaf(x, wb.z, cv[6][pw]);
            cv[7][pw] = fmaf(x, wb.w, cv[7][pw]);
          }
        }
      }
    }
    #pragma unroll
    for (int j = 0; j < 8; ++j) {
      float m = cv[j][0];
      #pragma unroll
      for (int pw = 1; pw < 7; ++pw) m = fmaxf(m, cv[j][pw]);
      m8[j] = m;
    }
  }
  __syncthreads();           // compute done; safe to overwrite weight LDS with partial-max buffer
  if (active) {
    #pragma unroll
    for (int j = 0; j < 8; ++j)
      sW[((cog*38 + pc)*7 + ph)*8 + j] = m8[j];
  }
  __syncthreads();
  for (int it = tid; it < 608; it += 576) {
    int pc2 = it % 38;
    int co  = it / 38;
    int cg  = co >> 3, j = co & 7;
    float m = -INFINITY;
    #pragma unroll
    for (int p = 0; p < 7; ++p)
      m = fmaxf(m, sW[((cg*38 + pc2)*7 + p)*8 + j]);
    out1[((n*16 + co)*38 + pr)*38 + pc2] = LEAKY(m);
  }
}

// ---------------- conv2 (16->32, 7x7, pad 0) + maxpool 5/3 + leaky ----------------
// block = (pr 0..9, n), 256 threads (200 active). Thread = (cog 0..3, pc 0..9, ph 0..4).
__global__ __launch_bounds__(256) void conv2_pool(
    const float* __restrict__ in, const float* __restrict__ w2r,
    const float* __restrict__ b2, float* __restrict__ out2)
{
  const int pr = blockIdx.x;
  const int n  = blockIdx.y;
  __shared__ float sIn[16][11][38];   // 6688 floats
  __shared__ float pm[1600];          // [4][10][5][8]
  const int tid = threadIdx.x;
  for (int idx = tid; idx < 6688; idx += 256) {
    int ci = idx / 418;
    int rem = idx - ci*418;
    int lr = rem / 38;
    int lc = rem - lr*38;
    sIn[ci][lr][lc] = in[((n*16 + ci)*38 + (3*pr + lr))*38 + lc];
  }
  __syncthreads();
  const bool active = tid < 200;
  int pc = 0, ph = 0, cog = 0;
  float m8[8];
  if (active) {
    pc  = tid % 10;
    ph  = (tid / 10) % 5;
    cog = tid / 50;
    float cv[8][5];
    #pragma unroll
    for (int j = 0; j < 8; ++j) {
      float bv = b2[cog*8 + j];
      #pragma unroll
      for (int pw = 0; pw < 5; ++pw) cv[j][pw] = bv;
    }
    for (int ci = 0; ci < 16; ++ci) {
      for (int kh = 0; kh < 7; ++kh) {
        const float* __restrict__ ip = &sIn[ci][ph + kh][3*pc];
        float xv[11];
        #pragma unroll
        for (int t = 0; t < 11; ++t) xv[t] = ip[t];
        const float4* __restrict__ wp = (const float4*)&w2r[(ci*7 + kh)*224 + cog*8];
        #pragma unroll
        for (int kw = 0; kw < 7; ++kw) {
          float4 wa = wp[kw*8];
          float4 wb = wp[kw*8 + 1];
          #pragma unroll
          for (int pw = 0; pw < 5; ++pw) {
            float x = xv[pw + kw];
            cv[0][pw] = fmaf(x, wa.x, cv[0][pw]);
            cv[1][pw] = fmaf(x, wa.y, cv[1][pw]);
            cv[2][pw] = fmaf(x, wa.z, cv[2][pw]);
            cv[3][pw] = fmaf(x, wa.w, cv[3][pw]);
            cv[4][pw] = fmaf(x, wb.x, cv[4][pw]);
            cv[5][pw] = fmaf(x, wb.y, cv[5][pw]);
            cv[6][pw] = fmaf(x, wb.z, cv[6][pw]);
            cv[7][pw] = fmaf(x, wb.w, cv[7][pw]);
          }
        }
      }
    }
    #pragma unroll
    for (int j = 0; j < 8; ++j) {
      float m = cv[j][0];
      #pragma unroll
      for (int pw = 1; pw < 5; ++pw) m = fmaxf(m, cv[j][pw]);
      m8[j] = m;
    }
  }
  __syncthreads();
  if (active) {
    #pragma unroll
    for (int j = 0; j < 8; ++j)
      pm[((cog*10 + pc)*5 + ph)*8 + j] = m8[j];
  }
  __syncthreads();
  for (int it = tid; it < 320; it += 256) {
    int pc2 = it % 10;
    int co  = it / 10;
    int cg  = co >> 3, j = co & 7;
    float m = -INFINITY;
    #pragma unroll
    for (int p = 0; p < 5; ++p)
      m = fmaxf(m, pm[((cg*10 + pc2)*5 + p)*8 + j]);
    out2[((n*32 + co)*10 + pr)*10 + pc2] = LEAKY(m);
  }
}

// ---------------- conv3 (32->64, 5x5, pad 0) + maxpool 3/2 + leaky ----------------
// block = n, 256 threads. Thread = (pos 0..3 -> (py,px), co 0..63).
__global__ __launch_bounds__(256) void conv3_pool(
    const float* __restrict__ in, const float* __restrict__ w3r,
    const float* __restrict__ b3, float* __restrict__ out3)
{
  const int n = blockIdx.x;
  __shared__ float sIn[3200];
  const int tid = threadIdx.x;
  for (int idx = tid; idx < 3200; idx += 256)
    sIn[idx] = in[n*3200 + idx];
  __syncthreads();
  const int co  = tid & 63;
  const int pos = tid >> 6;
  const int py = pos >> 1, px = pos & 1;
  float acc[3][3];
  float bv = b3[co];
  #pragma unroll
  for (int dy = 0; dy < 3; ++dy)
    #pragma unroll
    for (int dx = 0; dx < 3; ++dx) acc[dy][dx] = bv;
  for (int ci = 0; ci < 32; ++ci) {
    for (int kh = 0; kh < 5; ++kh) {
      float xr[3][7];
      #pragma unroll
      for (int dy = 0; dy < 3; ++dy)
        #pragma unroll
        for (int cc = 0; cc < 7; ++cc)
          xr[dy][cc] = sIn[ci*100 + (2*py + kh + dy)*10 + (2*px + cc)];
      #pragma unroll
      for (int kw = 0; kw < 5; ++kw) {
        float w = w3r[(ci*25 + kh*5 + kw)*64 + co];
        #pragma unroll
        for (int dy = 0; dy < 3; ++dy)
          #pragma unroll
          for (int dx = 0; dx < 3; ++dx)
            acc[dy][dx] = fmaf(xr[dy][dx + kw], w, acc[dy][dx]);
      }
    }
  }
  float m = -INFINITY;
  #pragma unroll
  for (int dy = 0; dy < 3; ++dy)
    #pragma unroll
    for (int dx = 0; dx < 3; ++dx) m = fmaxf(m, acc[dy][dx]);
  out3[n*256 + co*4 + py*2 + px] = LEAKY(m);
}

// ---------------- attention: per (b,h): Q,K,V -> omega -> softmax(axis=s) -> Z ----------------
__global__ __launch_bounds__(64) void attn_kernel(
    const float* __restrict__ Y, const float* __restrict__ Wq,
    const float* __restrict__ Wk, const float* __restrict__ Wv,
    float* __restrict__ Zc)
{
  const int h = blockIdx.x;   // 0..15
  const int b = blockIdx.y;   // 0..7
  __shared__ float sQ[30][2], sK[30][2], sV[30][4], sA[30][30];
  const int t = threadIdx.x;
  for (int it = t; it < 240; it += 64) {
    if (it < 60) {
      int s = it >> 1, q = it & 1;
      const float* yp = &Y[(b*30 + s)*256];
      const float* wp = &Wq[h*512 + q];
      float acc = 0.f;
      for (int e = 0; e < 256; ++e) acc += yp[e]*wp[e*2];
      sQ[s][q] = acc;
    } else if (it < 120) {
      int r = it - 60;
      int s = r >> 1, q = r & 1;
      const float* yp = &Y[(b*30 + s)*256];
      const float* wp = &Wk[h*512 + q];
      float acc = 0.f;
      for (int e = 0; e < 256; ++e) acc += yp[e]*wp[e*2];
      sK[s][q] = acc;
    } else {
      int r = it - 120;
      int s = r >> 2, v = r & 3;
      const float* yp = &Y[(b*30 + s)*256];
      const float* wp = &Wv[h*1024 + v];
      float acc = 0.f;
      for (int e = 0; e < 256; ++e) acc += yp[e]*wp[e*4];
      sV[s][v] = acc;
    }
  }
  __syncthreads();
  for (int it = t; it < 900; it += 64) {
    int si = it / 30, tj = it - si*30;
    sA[si][tj] = (sQ[si][0]*sK[tj][0] + sQ[si][1]*sK[tj][1]) * 0.70710678118654752f;
  }
  __syncthreads();
  if (t < 30) {                       // softmax over axis s (rows), per column t
    float m = -INFINITY;
    for (int si = 0; si < 30; ++si) m = fmaxf(m, sA[si][t]);
    float sum = 0.f;
    for (int si = 0; si < 30; ++si) {
      float v = expf(sA[si][t] - m);
      sA[si][t] = v;
      sum += v;
    }
    float inv = 1.f/sum;
    for (int si = 0; si < 30; ++si) sA[si][t] *= inv;
  }
  __syncthreads();
  for (int it = t; it < 120; it += 64) {
    int si = it >> 2, v = it & 3;
    float z = 0.f;
    for (int tt = 0; tt < 30; ++tt) z += sA[si][tt]*sV[tt][v];
    Zc[(b*30 + si)*64 + h*4 + v] = z;
  }
}

// ---------------- final linear [8,1920]x[1920,10] + softmax ----------------
__global__ __launch_bounds__(256) void head_kernel(
    const float* __restrict__ Zc, const float* __restrict__ Wr,
    const float* __restrict__ br, float* __restrict__ out)
{
  const int b = blockIdx.x;
  __shared__ float red[240];
  __shared__ float logit[10];
  const int t = threadIdx.x;
  if (t < 240) {
    int o = t / 24, j = t - o*24;
    const float* zp = &Zc[b*1920 + j*80];
    const float* wp = &Wr[o*1920 + j*80];
    float s = 0.f;
    for (int k = 0; k < 80; ++k) s += zp[k]*wp[k];
    red[t] = s;
  }
  __syncthreads();
  if (t < 10) {
    float s = br[t];
    #pragma unroll
    for (int j = 0; j < 24; ++j) s += red[t*24 + j];
    logit[t] = s;
  }
  __syncthreads();
  if (t == 0) {
    float m = -INFINITY;
    for (int o = 0; o < 10; ++o) m = fmaxf(m, logit[o]);
    float sum = 0.f;
    float ex[10];
    for (int o = 0; o < 10; ++o) { ex[o] = expf(logit[o] - m); sum += ex[o]; }
    float inv = 1.f/sum;
    for (int o = 0; o < 10; ++o) out[b*10 + o] = ex[o]*inv;
  }
}

extern "C" void kernel_launch(void* const* d_in, const int* in_sizes, int n_in,
                              void* d_out, int out_size, void* d_ws, size_t ws_size,
                              hipStream_t stream) {
  const float* X  = (const float*)d_in[0];
  const float* W1 = (const float*)d_in[1];
  const float* b1 = (const float*)d_in[2];
  const float* W2 = (const float*)d_in[3];
  const float* b2 = (const float*)d_in[4];
  const float* W3 = (const float*)d_in[5];
  const float* b3 = (const float*)d_in[6];
  const float* Wq = (const float*)d_in[7];
  const float* Wk = (const float*)d_in[8];
  const float* Wv = (const float*)d_in[9];
  const float* Wr = (const float*)d_in[10];
  const float* br = (const float*)d_in[11];

  float* ws  = (float*)d_ws;
  float* w2r = ws;                         // 25088
  float* w3r = ws + 25088;                 // 51200
  float* o1  = ws + 76288;                 // 240*16*38*38 = 5544960
  float* o2  = ws + 5621248;               // 240*32*10*10 = 768000
  float* o3  = ws + 6389248;               // 240*256      = 61440
  float* zc  = ws + 6450688;               // 8*30*64      = 15360

  prep_weights<<<dim3(200), dim3(256), 0, stream>>>(W2, W3, w2r, w3r);
  conv1_pool  <<<dim3(38, 240), dim3(576), 0, stream>>>(X, W1, b1, o1);
  conv2_pool  <<<dim3(10, 240), dim3(256), 0, stream>>>(o1, w2r, b2, o2);
  conv3_pool  <<<dim3(240),     dim3(256), 0, stream>>>(o2, w3r, b3, o3);
  attn_kernel <<<dim3(16, 8),   dim3(64),  0, stream>>>(o3, Wq, Wk, Wv, zc);
  head_kernel <<<dim3(8),       dim3(256), 0, stream>>>(zc, Wr, br, (float*)d_out);
}

// Round 5
// 1131.654 us; speedup vs baseline: 2.5246x; 2.5246x over previous
//
#include <hip/hip_runtime.h>
#include <math.h>

#define LEAKY(x) ((x) > 0.0f ? (x) : 0.01f*(x))

typedef __attribute__((ext_vector_type(8))) short bfrag8;    // 8 bf16 in 4 VGPRs
typedef __attribute__((ext_vector_type(16))) float accv16;   // MFMA 32x32 accumulator

// round-to-nearest-even fp32 -> bf16 (as ushort)
__device__ __forceinline__ unsigned short bfr(float x) {
  unsigned int u = __float_as_uint(x);
  unsigned int r = u + 0x7fffu + ((u >> 16) & 1u);
  return (unsigned short)(r >> 16);
}

// k-slot labeling for v_mfma_f32_32x32x16_bf16 A/B operands. NOTE: any bijection
// works as long as A and B use the same labeling (sum over k is permutation-
// invariant); this one matches the two-concatenated-K-halves structure.
#define KMAP(lh, j) (8*((j)>>2) + 4*(lh) + ((j)&3))

// ---------------- prep: W2/W3 relayout + conv1 B-fragment gather ----------------
// B-frag f = hl*10 + kwh*2 + ks  (hl: 0=hi,1=lo; kwh 0..4; ks = K-step 0..1)
// lane l: n = l&31 -> (co = n&15, p = n>>4); elem j: k = ks*16 + KMAP(l>>5, j)
// value = W1[co][ci=k/9][kh=k%9][kw=2*kwh+p]  (0 if k>=27 or kw>8), split hi/lo bf16.
__global__ __launch_bounds__(256) void prep_weights(
    const float* __restrict__ W2, const float* __restrict__ W3,
    const float* __restrict__ W1,
    float* __restrict__ w2r, float* __restrict__ w3r,
    unsigned short* __restrict__ bfrag)
{
  int i = blockIdx.x*256 + threadIdx.x;
  if (i < 25088) {
    int co = i & 31; int k = i >> 5;
    w2r[k*32 + co] = W2[co*784 + k];
  }
  if (i < 51200) {
    int co = i & 63; int k = i >> 6;
    w3r[k*64 + co] = W3[co*800 + k];
  }
  if (i < 1280) {
    int lane = i & 63;
    int f = i >> 6;                 // 0..19
    int hl = f / 10;
    int rem = f - hl*10;
    int kwh = rem >> 1;
    int ks  = rem & 1;
    int nn = lane & 31;
    int co = nn & 15, p = nn >> 4;
    int lh = (lane >> 5) & 1;
    #pragma unroll
    for (int j = 0; j < 8; ++j) {
      int k = ks*16 + KMAP(lh, j);
      float wv = 0.f;
      if (k < 27) {
        int ci = k / 9, kh = k - ci*9;
        int kw = 2*kwh + p;
        if (kw <= 8) wv = W1[((co*3 + ci)*9 + kh)*9 + kw];
      }
      unsigned short h = bfr(wv);
      unsigned short outv;
      if (hl == 0) outv = h;
      else {
        float hf = __uint_as_float(((unsigned int)h) << 16);
        outv = bfr(wv - hf);
      }
      bfrag[(f*64 + lane)*8 + j] = outv;
    }
  }
}

// ---------------- conv1 (3->16, 9x9, pad 1) + maxpool 7/5 + leaky via MFMA ----------------
// Block = (pr 0..37, n 0..239), 512 threads = 8 waves. Waves 0..6 own M-tiles m0=32w
// (m = conv output col index space, m 0..193 useful). Per conv row r = 5*pr+ph:
//   build LDS A-planes pl[ks][lh][208][8] bf16 (hi & lo): elem j at col c holds
//     k = ks*16 + KMAP(lh,j) = (ci*9+kh), value = X[n][ci][r-1+kh][c-1] (0 outside).
//   MFMA: for ks(2) x kwh(5): A-frag col = m0+(lane&31)+2*kwh (clamped), 3 split-term MFMAs.
//   O'[m,(co,p)] -> rowbuf; fold: O[x,co]=rowbuf[x][0][co]+rowbuf[x+1][1][co],
//   max over 7x7 window accumulated into pm; epilogue adds bias + leaky.
__global__ __launch_bounds__(512, 2) void conv1_mfma(
    const float* __restrict__ X, const float* __restrict__ b1,
    const unsigned short* __restrict__ bfrag, float* __restrict__ out1)
{
  const int pr = blockIdx.x;
  const int n  = blockIdx.y;
  const int tid = threadIdx.x;
  const int lane = tid & 63;
  const int w = tid >> 6;

  __shared__ unsigned short plh[2][2][208][8];
  __shared__ unsigned short pll[2][2][208][8];
  __shared__ float rowbuf[200][2][17];
  __shared__ float pm[38][17];

  // B fragments -> registers (static indices only)
  bfrag8 Bf[20];
  #pragma unroll
  for (int f = 0; f < 20; ++f)
    Bf[f] = *(const bfrag8*)&bfrag[(f*64 + lane)*8];

  // pm init: 608 = 38*16 entries, block has 512 threads -> MUST loop (r3/r4 bug:
  // `if (tid<608)` left rows 32..37 uninitialized -> garbage in fmax accumulate)
  for (int t = tid; t < 608; t += 512)
    pm[t >> 4][t & 15] = -INFINITY;

  const float* __restrict__ Xn = X + (size_t)n * 120000;

  for (int ph = 0; ph < 7; ++ph) {
    const int r = 5*pr + ph;

    // ---- build A-planes (hi & lo) for this conv row ----
    for (int t = tid; t < 832; t += 512) {
      int q = t / 208;            // q = ks*2 + lh
      int c = t - q*208;
      int ks = q >> 1, lh = q & 1;
      int colX = c - 1;
      bool cok = (unsigned)colX < 200u;
      bfrag8 H, L;
      #pragma unroll
      for (int j = 0; j < 8; ++j) {
        int k = ks*16 + KMAP(lh, j);
        float x = 0.f;
        if (k < 27) {
          int ci = (k * 57) >> 9;          // k/9 for k<27
          int kh = k - ci*9;
          int row = r - 1 + kh;
          if (cok && (unsigned)row < 200u)
            x = Xn[(ci*200 + row)*200 + colX];
        }
        unsigned short h = bfr(x);
        float hf = __uint_as_float(((unsigned int)h) << 16);
        unsigned short l = bfr(x - hf);
        H[j] = (short)h;
        L[j] = (short)l;
      }
      *(bfrag8*)&plh[ks][lh][c][0] = H;
      *(bfrag8*)&pll[ks][lh][c][0] = L;
    }
    __syncthreads();

    // ---- MFMA phase: wave w computes M-tile m0 = 32*w ----
    if (w < 7) {
      const int m0 = w*32;
      const int lh = (lane >> 5) & 1;
      const int mi = lane & 31;
      accv16 C;
      #pragma unroll
      for (int e = 0; e < 16; ++e) C[e] = 0.f;

      #pragma unroll
      for (int ks = 0; ks < 2; ++ks) {
        #pragma unroll
        for (int kwh = 0; kwh < 5; ++kwh) {
          int col = m0 + mi + 2*kwh;
          col = col > 207 ? 207 : col;
          bfrag8 ah = *(const bfrag8*)&plh[ks][lh][col][0];
          bfrag8 al = *(const bfrag8*)&pll[ks][lh][col][0];
          C = __builtin_amdgcn_mfma_f32_32x32x16_bf16(ah, Bf[kwh*2 + ks],      C, 0, 0, 0); // xh*wh
          C = __builtin_amdgcn_mfma_f32_32x32x16_bf16(ah, Bf[10 + kwh*2 + ks], C, 0, 0, 0); // xh*wl
          C = __builtin_amdgcn_mfma_f32_32x32x16_bf16(al, Bf[kwh*2 + ks],      C, 0, 0, 0); // xl*wh
        }
      }
      const int co = lane & 15, p = (lane >> 4) & 1;
      #pragma unroll
      for (int reg = 0; reg < 16; ++reg) {
        int m = m0 + (reg & 3) + 8*(reg >> 2) + 4*lh;
        if (m < 200) rowbuf[m][p][co] = C[reg];
      }
    }
    __syncthreads();

    // ---- pool update: 304 (pc, co-pair) items ----
    for (int t = tid; t < 304; t += 512) {
      int c2 = t & 7, pc = t >> 3;
      int u0 = 5*pc;
      float s0 = -INFINITY, s1 = -INFINITY;
      #pragma unroll
      for (int pw = 0; pw < 7; ++pw) {
        const float* r0 = &rowbuf[u0+pw][0][c2*2];
        const float* r1 = &rowbuf[u0+pw+1][1][c2*2];
        float v0 = r0[0] + r1[0];
        float v1 = r0[1] + r1[1];
        s0 = fmaxf(s0, v0); s1 = fmaxf(s1, v1);
      }
      pm[pc][c2*2]   = fmaxf(pm[pc][c2*2],   s0);
      pm[pc][c2*2+1] = fmaxf(pm[pc][c2*2+1], s1);
    }
    __syncthreads();
  }

  for (int t = tid; t < 608; t += 512) {
    int co = t & 15, pc = t >> 4;
    float v = pm[pc][co] + b1[co];
    out1[((n*16 + co)*38 + pr)*38 + pc] = LEAKY(v);
  }
}

// ---------------- conv2 (16->32, 7x7, pad 0) + maxpool 5/3 + leaky ----------------
__global__ __launch_bounds__(256) void conv2_pool(
    const float* __restrict__ in, const float* __restrict__ w2r,
    const float* __restrict__ b2, float* __restrict__ out2)
{
  const int pr = blockIdx.x;
  const int n  = blockIdx.y;
  __shared__ float sIn[16][11][38];
  __shared__ float pm[1600];
  const int tid = threadIdx.x;
  for (int idx = tid; idx < 6688; idx += 256) {
    int ci = idx / 418;
    int rem = idx - ci*418;
    int lr = rem / 38;
    int lc = rem - lr*38;
    sIn[ci][lr][lc] = in[((n*16 + ci)*38 + (3*pr + lr))*38 + lc];
  }
  __syncthreads();
  const bool active = tid < 200;
  int pc = 0, ph = 0, cog = 0;
  float m8[8];
  if (active) {
    pc  = tid % 10;
    ph  = (tid / 10) % 5;
    cog = tid / 50;
    float cv[8][5];
    #pragma unroll
    for (int j = 0; j < 8; ++j) {
      float bv = b2[cog*8 + j];
      #pragma unroll
      for (int pw = 0; pw < 5; ++pw) cv[j][pw] = bv;
    }
    for (int ci = 0; ci < 16; ++ci) {
      for (int kh = 0; kh < 7; ++kh) {
        const float* __restrict__ ip = &sIn[ci][ph + kh][3*pc];
        float xv[11];
        #pragma unroll
        for (int t = 0; t < 11; ++t) xv[t] = ip[t];
        const float4* __restrict__ wp = (const float4*)&w2r[(ci*7 + kh)*224 + cog*8];
        #pragma unroll
        for (int kw = 0; kw < 7; ++kw) {
          float4 wa = wp[kw*8];
          float4 wb = wp[kw*8 + 1];
          #pragma unroll
          for (int pw = 0; pw < 5; ++pw) {
            float x = xv[pw + kw];
            cv[0][pw] = fmaf(x, wa.x, cv[0][pw]);
            cv[1][pw] = fmaf(x, wa.y, cv[1][pw]);
            cv[2][pw] = fmaf(x, wa.z, cv[2][pw]);
            cv[3][pw] = fmaf(x, wa.w, cv[3][pw]);
            cv[4][pw] = fmaf(x, wb.x, cv[4][pw]);
            cv[5][pw] = fmaf(x, wb.y, cv[5][pw]);
            cv[6][pw] = fmaf(x, wb.z, cv[6][pw]);
            cv[7][pw] = fmaf(x, wb.w, cv[7][pw]);
          }
        }
      }
    }
    #pragma unroll
    for (int j = 0; j < 8; ++j) {
      float m = cv[j][0];
      #pragma unroll
      for (int pw = 1; pw < 5; ++pw) m = fmaxf(m, cv[j][pw]);
      m8[j] = m;
    }
  }
  __syncthreads();
  if (active) {
    #pragma unroll
    for (int j = 0; j < 8; ++j)
      pm[((cog*10 + pc)*5 + ph)*8 + j] = m8[j];
  }
  __syncthreads();
  for (int it = tid; it < 320; it += 256) {
    int pc2 = it % 10;
    int co  = it / 10;
    int cg  = co >> 3, j = co & 7;
    float m = -INFINITY;
    #pragma unroll
    for (int p = 0; p < 5; ++p)
      m = fmaxf(m, pm[((cg*10 + pc2)*5 + p)*8 + j]);
    out2[((n*32 + co)*10 + pr)*10 + pc2] = LEAKY(m);
  }
}

// ---------------- conv3 (32->64, 5x5, pad 0) + maxpool 3/2 + leaky ----------------
__global__ __launch_bounds__(256) void conv3_pool(
    const float* __restrict__ in, const float* __restrict__ w3r,
    const float* __restrict__ b3, float* __restrict__ out3)
{
  const int n = blockIdx.x;
  __shared__ float sIn[3200];
  const int tid = threadIdx.x;
  for (int idx = tid; idx < 3200; idx += 256)
    sIn[idx] = in[n*3200 + idx];
  __syncthreads();
  const int co  = tid & 63;
  const int pos = tid >> 6;
  const int py = pos >> 1, px = pos & 1;
  float acc[3][3];
  float bv = b3[co];
  #pragma unroll
  for (int dy = 0; dy < 3; ++dy)
    #pragma unroll
    for (int dx = 0; dx < 3; ++dx) acc[dy][dx] = bv;
  for (int ci = 0; ci < 32; ++ci) {
    for (int kh = 0; kh < 5; ++kh) {
      float xr[3][7];
      #pragma unroll
      for (int dy = 0; dy < 3; ++dy)
        #pragma unroll
        for (int cc = 0; cc < 7; ++cc)
          xr[dy][cc] = sIn[ci*100 + (2*py + kh + dy)*10 + (2*px + cc)];
      #pragma unroll
      for (int kw = 0; kw < 5; ++kw) {
        float wv = w3r[(ci*25 + kh*5 + kw)*64 + co];
        #pragma unroll
        for (int dy = 0; dy < 3; ++dy)
          #pragma unroll
          for (int dx = 0; dx < 3; ++dx)
            acc[dy][dx] = fmaf(xr[dy][dx + kw], wv, acc[dy][dx]);
      }
    }
  }
  float m = -INFINITY;
  #pragma unroll
  for (int dy = 0; dy < 3; ++dy)
    #pragma unroll
    for (int dx = 0; dx < 3; ++dx) m = fmaxf(m, acc[dy][dx]);
  out3[n*256 + co*4 + py*2 + px] = LEAKY(m);
}

// ---------------- attention ----------------
__global__ __launch_bounds__(64) void attn_kernel(
    const float* __restrict__ Y, const float* __restrict__ Wq,
    const float* __restrict__ Wk, const float* __restrict__ Wv,
    float* __restrict__ Zc)
{
  const int h = blockIdx.x;
  const int b = blockIdx.y;
  __shared__ float sQ[30][2], sK[30][2], sV[30][4], sA[30][30];
  const int t = threadIdx.x;
  for (int it = t; it < 240; it += 64) {
    if (it < 60) {
      int s = it >> 1, q = it & 1;
      const float* yp = &Y[(b*30 + s)*256];
      const float* wp = &Wq[h*512 + q];
      float acc = 0.f;
      for (int e = 0; e < 256; ++e) acc += yp[e]*wp[e*2];
      sQ[s][q] = acc;
    } else if (it < 120) {
      int rr = it - 60;
      int s = rr >> 1, q = rr & 1;
      const float* yp = &Y[(b*30 + s)*256];
      const float* wp = &Wk[h*512 + q];
      float acc = 0.f;
      for (int e = 0; e < 256; ++e) acc += yp[e]*wp[e*2];
      sK[s][q] = acc;
    } else {
      int rr = it - 120;
      int s = rr >> 2, v = rr & 3;
      const float* yp = &Y[(b*30 + s)*256];
      const float* wp = &Wv[h*1024 + v];
      float acc = 0.f;
      for (int e = 0; e < 256; ++e) acc += yp[e]*wp[e*4];
      sV[s][v] = acc;
    }
  }
  __syncthreads();
  for (int it = t; it < 900; it += 64) {
    int si = it / 30, tj = it - si*30;
    sA[si][tj] = (sQ[si][0]*sK[tj][0] + sQ[si][1]*sK[tj][1]) * 0.70710678118654752f;
  }
  __syncthreads();
  if (t < 30) {
    float m = -INFINITY;
    for (int si = 0; si < 30; ++si) m = fmaxf(m, sA[si][t]);
    float sum = 0.f;
    for (int si = 0; si < 30; ++si) {
      float v = expf(sA[si][t] - m);
      sA[si][t] = v;
      sum += v;
    }
    float inv = 1.f/sum;
    for (int si = 0; si < 30; ++si) sA[si][t] *= inv;
  }
  __syncthreads();
  for (int it = t; it < 120; it += 64) {
    int si = it >> 2, v = it & 3;
    float z = 0.f;
    for (int tt = 0; tt < 30; ++tt) z += sA[si][tt]*sV[tt][v];
    Zc[(b*30 + si)*64 + h*4 + v] = z;
  }
}

// ---------------- final linear + softmax ----------------
__global__ __launch_bounds__(256) void head_kernel(
    const float* __restrict__ Zc, const float* __restrict__ Wr,
    const float* __restrict__ br, float* __restrict__ out)
{
  const int b = blockIdx.x;
  __shared__ float red[240];
  __shared__ float logit[10];
  const int t = threadIdx.x;
  if (t < 240) {
    int o = t / 24, j = t - o*24;
    const float* zp = &Zc[b*1920 + j*80];
    const float* wp = &Wr[o*1920 + j*80];
    float s = 0.f;
    for (int k = 0; k < 80; ++k) s += zp[k]*wp[k];
    red[t] = s;
  }
  __syncthreads();
  if (t < 10) {
    float s = br[t];
    #pragma unroll
    for (int j = 0; j < 24; ++j) s += red[t*24 + j];
    logit[t] = s;
  }
  __syncthreads();
  if (t == 0) {
    float m = -INFINITY;
    for (int o = 0; o < 10; ++o) m = fmaxf(m, logit[o]);
    float sum = 0.f;
    float ex[10];
    for (int o = 0; o < 10; ++o) { ex[o] = expf(logit[o] - m); sum += ex[o]; }
    float inv = 1.f/sum;
    for (int o = 0; o < 10; ++o) out[b*10 + o] = ex[o]*inv;
  }
}

extern "C" void kernel_launch(void* const* d_in, const int* in_sizes, int n_in,
                              void* d_out, int out_size, void* d_ws, size_t ws_size,
                              hipStream_t stream) {
  const float* X  = (const float*)d_in[0];
  const float* W1 = (const float*)d_in[1];
  const float* b1 = (const float*)d_in[2];
  const float* W2 = (const float*)d_in[3];
  const float* b2 = (const float*)d_in[4];
  const float* W3 = (const float*)d_in[5];
  const float* b3 = (const float*)d_in[6];
  const float* Wq = (const float*)d_in[7];
  const float* Wk = (const float*)d_in[8];
  const float* Wv = (const float*)d_in[9];
  const float* Wr = (const float*)d_in[10];
  const float* br = (const float*)d_in[11];

  float* ws  = (float*)d_ws;
  float* w2r = ws;                          // 25088
  float* w3r = ws + 25088;                  // 51200
  unsigned short* bfrag = (unsigned short*)(ws + 76288);  // 10240 ushort = 5120 floats
  float* o1  = ws + 81408;                  // 240*16*38*38 = 5544960
  float* o2  = ws + 5626368;                // 240*32*10*10 = 768000
  float* o3  = ws + 6394368;                // 240*256      = 61440
  float* zc  = ws + 6455808;                // 8*30*64      = 15360

  prep_weights<<<dim3(200), dim3(256), 0, stream>>>(W2, W3, W1, w2r, w3r, bfrag);
  conv1_mfma  <<<dim3(38, 240), dim3(512), 0, stream>>>(X, b1, bfrag, o1);
  conv2_pool  <<<dim3(10, 240), dim3(256), 0, stream>>>(o1, w2r, b2, o2);
  conv3_pool  <<<dim3(240),     dim3(256), 0, stream>>>(o2, w3r, b3, o3);
  attn_kernel <<<dim3(16, 8),   dim3(64),  0, stream>>>(o3, Wq, Wk, Wv, zc);
  head_kernel <<<dim3(8),       dim3(256), 0, stream>>>(zc, Wr, br, (float*)d_out);
}